// Round 4
// baseline (238.164 us; speedup 1.0000x reference)
//
#include <hip/hip_runtime.h>

// TT embedding lookup, fused single-kernel (binning redone per block).
// P=(216,216,216), Q=(2,4,2), R=(128,128), tables=2, batch=1024.
// core0: [2,216,256]   (A row:  [Q0=2][R0=128])
// core1: [2,216,65536] (Bm row: [R0=128][S=512], S = q1*128 + r1)
// core2: [2,216,256]   (C row:  [R1=128][Q2=2])
// out:   [2,1024,16]
//
// Grid (432 groups, 4 q-quarters, 2 chunk-slots) x 128 threads (2 waves =
// r-halves).  Deterministic ballot-scan binning per block (round-2 lesson:
// atomic orders diverge across blocks).
//
// Round-3 lesson: VGPR_Count=52 => compiler rolled the FMA loop into
// load->vmcnt(0)->consume; warm-cache replay still took 70us => kernel was
// EXPOSED-LATENCY bound, not BW bound.  This version forces a deep load
// pipeline: __launch_bounds__(128,4) (VGPR<=128) + explicit 2x16 float2
// register double-buffer for B (statically indexed, fully unrolled phases)
// and register-staged A (16 independent loads up-front, then ds_write_b64).

#define CAP  48          // Binomial(1024,1/216): mean 4.74, P(m>48) ~ 0
#define CAPP (CAP + 8)   // pad: s_aux[base+l] is read blindly for l<8

__global__ __launch_bounds__(128, 4) void tt_fused(
    const int* __restrict__ idx32,
    const float* __restrict__ c0,
    const float* __restrict__ c1,
    const float* __restrict__ c2,
    float* __restrict__ out)
{
    const int g     = blockIdx.x;      // group id [0,432) = table*216 + i1
    const int q     = blockIdx.y;      // s-quarter {0..3} == q1
    const int cs    = blockIdx.z;      // chunk slot {0,1}
    const int table = g / 216;
    const int i1    = g - table * 216;

    const int tid = threadIdx.x;
    const int rh  = tid >> 6;          // r-half: wave0 r<64, wave1 r>=64
    const int tl  = tid & 63;

    // 8 KB LDS, dual-purpose: A staging ([l][r] float2 = (A0,A1)) during the
    // FMA loop; wave1's partial accumulators during the r-split combine.
    __shared__ float lds[2048];
    __shared__ int s_id[CAPP];
    __shared__ int s_aux[CAPP];        // (i0<<16)|i2 ; pad rows -> row 0
    __shared__ int s_cnt;

    if (tid < CAPP) s_aux[tid] = 0;

    // int64-vs-int32 buffer detection (values < 2^31 => odd words zero in LE)
    const bool is64 = (idx32[1] == 0) & (idx32[3] == 0) &
                      (idx32[5] == 0) & (idx32[7] == 0);

    // deterministic scan: wave0 only, j ascending in 16 ballot-steps of 64.
    if (rh == 0) {
        int cnt = 0;
#pragma unroll
        for (int it = 0; it < 16; ++it) {
            const int j  = it * 64 + tl;
            const int id = (table << 10) + j;
            const unsigned idx = is64 ? (unsigned)((const long long*)idx32)[id]
                                      : (unsigned)idx32[id];
            const unsigned i0  = idx / 46656u;       // magic-mul (idx < 2^24)
            const unsigned rem = idx - i0 * 46656u;
            const unsigned bi1 = rem / 216u;
            const bool match = ((int)bi1 == i1);
            const unsigned long long mask = __ballot(match);
            if (match) {
                const int pos = cnt + __popcll(mask & ((1ull << tl) - 1ull));
                if (pos < CAP) {
                    const unsigned i2 = rem - bi1 * 216u;
                    s_id[pos]  = id;
                    s_aux[pos] = (int)((i0 << 16) | i2);
                }
            }
            cnt += (int)__popcll(mask);              // uniform across wave
        }
        if (tl == 0) s_cnt = cnt;
    }
    __syncthreads();
    const int m = min(s_cnt, CAP);
    if (m <= cs * 8) return;           // cs=1 idle for ~95% of groups

    float2*       lds2 = (float2*)lds;
    const float4* lds4 = (const float4*)lds;

    // lane owns cols s = 128*q + 2*tl (+1); float2 index into row: r*256+64q+tl
    const float2* b2 = (const float2*)(c1 + ((size_t)g << 16))
                       + (size_t)rh * 64 * 256 + (q * 64 + tl);
    const float* c0t = c0 + (size_t)table * 216 * 256;

    // B-batch register pipeline: batch B covers this wave's r = B*16..B*16+15.
#define LOAD_BATCH(BUF, B)                                                  \
    _Pragma("unroll")                                                       \
    for (int i = 0; i < 16; ++i) BUF[i] = b2[(size_t)((B) * 16 + i) * 256];

#define FMA_BATCH(BUF, B)                                                   \
    _Pragma("unroll")                                                       \
    for (int i2 = 0; i2 < 8; ++i2) {                                        \
        const float2 bv0 = BUF[2 * i2];                                     \
        const float2 bv1 = BUF[2 * i2 + 1];                                 \
        const int rhalf = rh * 32 + (B) * 8 + i2;                           \
        _Pragma("unroll")                                                   \
        for (int l = 0; l < 8; ++l) {                                       \
            const float4 av = lds4[l * 64 + rhalf];                         \
            /* av = (A0[r],A1[r],A0[r+1],A1[r+1]) broadcast */              \
            acc[l][0].x += av.x * bv0.x; acc[l][0].y += av.x * bv0.y;       \
            acc[l][1].x += av.y * bv0.x; acc[l][1].y += av.y * bv0.y;       \
            acc[l][0].x += av.z * bv1.x; acc[l][0].y += av.z * bv1.y;       \
            acc[l][1].x += av.w * bv1.x; acc[l][1].y += av.w * bv1.y;       \
        }                                                                   \
    }

    for (int base = cs * 8; base < m; base += 16) {
        const int cl = min(8, m - base);
        __syncthreads();               // previous pass's LDS reads done

        // stage A through regs: 16 independent loads issued up-front
        // (thread tid owns r=tid: loads A[0][r], A[1][r] of each row)
        float a0[8], a1[8];
#pragma unroll
        for (int l = 0; l < 8; ++l) {
            const float* ar = c0t + (size_t)(s_aux[base + l] >> 16) * 256;
            a0[l] = ar[tid];           // q0=0
            a1[l] = ar[tid + 128];     // q0=1
        }

        float2 bva[16], bvb[16];
        LOAD_BATCH(bva, 0)             // issue B batch 0 behind the A loads

        // merged ds_write_b64: lds2[l*128 + r] = (A0[r], A1[r]); 2-way = free
#pragma unroll
        for (int l = 0; l < 8; ++l)
            lds2[l * 128 + tid] = make_float2(a0[l], a1[l]);
        __syncthreads();

        float2 acc[8][2];
#pragma unroll
        for (int l = 0; l < 8; ++l) {
            acc[l][0] = make_float2(0.f, 0.f);
            acc[l][1] = make_float2(0.f, 0.f);
        }

        // software-pipelined: 16 loads in flight while previous batch FMAs
        LOAD_BATCH(bvb, 1)
        FMA_BATCH(bva, 0)
        LOAD_BATCH(bva, 2)
        FMA_BATCH(bvb, 1)
        LOAD_BATCH(bvb, 3)
        FMA_BATCH(bva, 2)
        FMA_BATCH(bvb, 3)

        // r-split combine: wave1 -> LDS (A region dead now), wave0 adds.
        __syncthreads();
        if (rh == 1) {
#pragma unroll
            for (int l = 0; l < 8; ++l) {
                lds2[(l * 2 + 0) * 64 + tl] = acc[l][0];
                lds2[(l * 2 + 1) * 64 + tl] = acc[l][1];
            }
        }
        __syncthreads();

        if (rh == 0) {
#pragma unroll
            for (int l = 0; l < 8; ++l) {
                const float2 t0 = lds2[(l * 2 + 0) * 64 + tl];
                const float2 t1 = lds2[(l * 2 + 1) * 64 + tl];
                const float a0x = acc[l][0].x + t0.x, a0y = acc[l][0].y + t0.y;
                const float a1x = acc[l][1].x + t1.x, a1y = acc[l][1].y + t1.y;
                if (l < cl) {
                    // lane's r1 = 2*tl, 2*tl+1; C[r1][j] at crow[r1*2+j]
                    const float* crow =
                        c2 + (size_t)(table * 216 + (s_aux[base + l] & 0xffff)) * 256;
                    const float4 cv = *(const float4*)(crow + 4 * tl);
                    float p00 = a0x * cv.x + a0y * cv.z;
                    float p01 = a0x * cv.y + a0y * cv.w;
                    float p10 = a1x * cv.x + a1y * cv.z;
                    float p11 = a1x * cv.y + a1y * cv.w;
#pragma unroll
                    for (int mm = 32; mm >= 1; mm >>= 1) {
                        p00 += __shfl_xor(p00, mm);
                        p01 += __shfl_xor(p01, mm);
                        p10 += __shfl_xor(p10, mm);
                        p11 += __shfl_xor(p11, mm);
                    }
                    if (tl == 0) {
                        float* o = out + (size_t)s_id[base + l] * 16;
                        *(float2*)(o + q * 2)     = make_float2(p00, p01);  // q0=0
                        *(float2*)(o + 8 + q * 2) = make_float2(p10, p11);  // q0=1
                    }
                }
            }
        }
    }
#undef LOAD_BATCH
#undef FMA_BATCH
}

extern "C" void kernel_launch(void* const* d_in, const int* in_sizes, int n_in,
                              void* d_out, int out_size, void* d_ws, size_t ws_size,
                              hipStream_t stream) {
    const int*   idx = (const int*)d_in[0];
    const float* c0  = (const float*)d_in[1];
    const float* c1  = (const float*)d_in[2];
    const float* c2  = (const float*)d_in[3];
    float* out = (float*)d_out;
    (void)d_ws; (void)ws_size; (void)in_sizes; (void)n_in; (void)out_size;

    tt_fused<<<dim3(432, 4, 2), dim3(128), 0, stream>>>(idx, c0, c1, c2, out);
}

// Round 5
// 198.203 us; speedup vs baseline: 1.2016x; 1.2016x over previous
//
#include <hip/hip_runtime.h>

// TT embedding lookup, fused single-kernel (binning redone per block).
// P=(216,216,216), Q=(2,4,2), R=(128,128), tables=2, batch=1024.
// core0: [2,216,256]   (A row:  [Q0=2][R0=128])
// core1: [2,216,65536] (Bm row: [R0=128][S=512], S = q1*128 + r1)
// core2: [2,216,256]   (C row:  [R1=128][Q2=2])
// out:   [2,1024,16]
//
// Grid (432 groups, 4 q-quarters, 2 chunk-slots) x 128 threads (2 waves =
// r-halves).  Deterministic ballot-scan binning per block (round-2 lesson:
// atomic orders diverge across blocks), run redundantly on BOTH waves
// (identical results; same-value LDS writes are benign) so neither idles.
//
// Round-3 lesson: warm-replay rows ran 70us at ~zero HBM bytes => kernel is
// EXPOSED-L3-LATENCY bound on the strided B loads (VGPR 52 => ~1-2 loads in
// flight).  Round-4 lesson: a 2x16 float2 buffer (64 VGPR) spilled to
// scratch (WRITE_SIZE 128KB -> 81MB, 119us).  This version: 2x8 float2
// register double-buffer (32 VGPR) + acc(32) + A-stage(16) ~ 95 live regs,
// 8 unrolled load/FMA phases per pass -> 8 loads always in flight, per-batch
// FMA (~512 cyc) covers one L3 latency.

#define CAP  48          // Binomial(1024,1/216): mean 4.74, P(m>48) ~ 0
#define CAPP (CAP + 8)   // pad: s_aux[base+l] is read blindly for l<8

__global__ __launch_bounds__(128) void tt_fused(
    const int* __restrict__ idx32,
    const float* __restrict__ c0,
    const float* __restrict__ c1,
    const float* __restrict__ c2,
    float* __restrict__ out)
{
    const int g     = blockIdx.x;      // group id [0,432) = table*216 + i1
    const int q     = blockIdx.y;      // s-quarter {0..3} == q1
    const int cs    = blockIdx.z;      // chunk slot {0,1}
    const int table = g / 216;
    const int i1    = g - table * 216;

    const int tid = threadIdx.x;
    const int rh  = tid >> 6;          // r-half: wave0 r<64, wave1 r>=64
    const int tl  = tid & 63;

    // 8 KB LDS, dual-purpose: A staging ([l][r] float2 = (A0,A1)) during the
    // FMA loop; wave1's partial accumulators during the r-split combine.
    __shared__ float lds[2048];
    __shared__ int s_id[CAPP];
    __shared__ int s_aux[CAPP];        // (i0<<16)|i2 ; pad rows -> row 0
    __shared__ int s_cnt;

    if (tid < CAPP) s_aux[tid] = 0;

    // int64-vs-int32 buffer detection (values < 2^31 => odd words zero in LE)
    const bool is64 = (idx32[1] == 0) & (idx32[3] == 0) &
                      (idx32[5] == 0) & (idx32[7] == 0);

    // deterministic scan, j ascending in 16 ballot-steps of 64; BOTH waves
    // execute it identically (same j's -> same masks -> same positions).
    {
        int cnt = 0;
#pragma unroll
        for (int it = 0; it < 16; ++it) {
            const int j  = it * 64 + tl;
            const int id = (table << 10) + j;
            const unsigned idx = is64 ? (unsigned)((const long long*)idx32)[id]
                                      : (unsigned)idx32[id];
            const unsigned i0  = idx / 46656u;       // magic-mul (idx < 2^24)
            const unsigned rem = idx - i0 * 46656u;
            const unsigned bi1 = rem / 216u;
            const bool match = ((int)bi1 == i1);
            const unsigned long long mask = __ballot(match);
            if (match) {
                const int pos = cnt + __popcll(mask & ((1ull << tl) - 1ull));
                if (pos < CAP) {
                    const unsigned i2 = rem - bi1 * 216u;
                    s_id[pos]  = id;
                    s_aux[pos] = (int)((i0 << 16) | i2);
                }
            }
            cnt += (int)__popcll(mask);              // uniform across wave
        }
        if (tl == 0) s_cnt = cnt;
    }
    __syncthreads();
    const int m = min(s_cnt, CAP);
    if (m <= cs * 8) return;           // cs=1 idle for ~95% of groups

    float2*       lds2 = (float2*)lds;
    const float4* lds4 = (const float4*)lds;

    // lane owns cols s = 128*q + 2*tl (+1); float2 index into row: r*256+64q+tl
    const float2* b2 = (const float2*)(c1 + ((size_t)g << 16))
                       + (size_t)rh * 64 * 256 + (q * 64 + tl);
    const float* c0t = c0 + (size_t)table * 216 * 256;

    // B register double-buffer: batch B covers this wave's rr = B*8..B*8+7.
#define LOAD_BATCH(BUF, B)                                                  \
    _Pragma("unroll")                                                       \
    for (int i = 0; i < 8; ++i) BUF[i] = b2[(size_t)((B) * 8 + i) * 256];

#define FMA_BATCH(BUF, B)                                                   \
    _Pragma("unroll")                                                       \
    for (int i2 = 0; i2 < 4; ++i2) {                                        \
        const float2 bv0 = BUF[2 * i2];                                     \
        const float2 bv1 = BUF[2 * i2 + 1];                                 \
        const int rhalf = rh * 32 + (B) * 4 + i2;                           \
        _Pragma("unroll")                                                   \
        for (int l = 0; l < 8; ++l) {                                       \
            const float4 av = lds4[l * 64 + rhalf];                         \
            /* av = (A0[r],A1[r],A0[r+1],A1[r+1]) broadcast */              \
            acc[l][0].x += av.x * bv0.x; acc[l][0].y += av.x * bv0.y;       \
            acc[l][1].x += av.y * bv0.x; acc[l][1].y += av.y * bv0.y;       \
            acc[l][0].x += av.z * bv1.x; acc[l][0].y += av.z * bv1.y;       \
            acc[l][1].x += av.w * bv1.x; acc[l][1].y += av.w * bv1.y;       \
        }                                                                   \
    }

    for (int base = cs * 8; base < m; base += 16) {
        const int cl = min(8, m - base);
        __syncthreads();               // previous pass's LDS reads done

        // stage A through regs: 16 independent loads issued up-front
        // (thread tid owns r=tid: loads A[0][r], A[1][r] of each row)
        float a0[8], a1[8];
#pragma unroll
        for (int l = 0; l < 8; ++l) {
            const float* ar = c0t + (size_t)(s_aux[base + l] >> 16) * 256;
            a0[l] = ar[tid];           // q0=0
            a1[l] = ar[tid + 128];     // q0=1
        }

        float2 bva[8], bvb[8];
        LOAD_BATCH(bva, 0)             // issue B batch 0 behind the A loads

        // merged ds_write_b64: lds2[l*128 + r] = (A0[r], A1[r]); 2-way = free
#pragma unroll
        for (int l = 0; l < 8; ++l)
            lds2[l * 128 + tid] = make_float2(a0[l], a1[l]);
        __syncthreads();

        float2 acc[8][2];
#pragma unroll
        for (int l = 0; l < 8; ++l) {
            acc[l][0] = make_float2(0.f, 0.f);
            acc[l][1] = make_float2(0.f, 0.f);
        }

        // software-pipelined: 8 loads in flight while previous batch FMAs
        LOAD_BATCH(bvb, 1)
        FMA_BATCH(bva, 0)
        LOAD_BATCH(bva, 2)
        FMA_BATCH(bvb, 1)
        LOAD_BATCH(bvb, 3)
        FMA_BATCH(bva, 2)
        LOAD_BATCH(bva, 4)
        FMA_BATCH(bvb, 3)
        LOAD_BATCH(bvb, 5)
        FMA_BATCH(bva, 4)
        LOAD_BATCH(bva, 6)
        FMA_BATCH(bvb, 5)
        LOAD_BATCH(bvb, 7)
        FMA_BATCH(bva, 6)
        FMA_BATCH(bvb, 7)

        // r-split combine: wave1 -> LDS (A region dead now), wave0 adds.
        __syncthreads();
        if (rh == 1) {
#pragma unroll
            for (int l = 0; l < 8; ++l) {
                lds2[(l * 2 + 0) * 64 + tl] = acc[l][0];
                lds2[(l * 2 + 1) * 64 + tl] = acc[l][1];
            }
        }
        __syncthreads();

        if (rh == 0) {
#pragma unroll
            for (int l = 0; l < 8; ++l) {
                const float2 t0 = lds2[(l * 2 + 0) * 64 + tl];
                const float2 t1 = lds2[(l * 2 + 1) * 64 + tl];
                const float a0x = acc[l][0].x + t0.x, a0y = acc[l][0].y + t0.y;
                const float a1x = acc[l][1].x + t1.x, a1y = acc[l][1].y + t1.y;
                if (l < cl) {
                    // lane's r1 = 2*tl, 2*tl+1; C[r1][j] at crow[r1*2+j]
                    const float* crow =
                        c2 + (size_t)(table * 216 + (s_aux[base + l] & 0xffff)) * 256;
                    const float4 cv = *(const float4*)(crow + 4 * tl);
                    float p00 = a0x * cv.x + a0y * cv.z;
                    float p01 = a0x * cv.y + a0y * cv.w;
                    float p10 = a1x * cv.x + a1y * cv.z;
                    float p11 = a1x * cv.y + a1y * cv.w;
#pragma unroll
                    for (int mm = 32; mm >= 1; mm >>= 1) {
                        p00 += __shfl_xor(p00, mm);
                        p01 += __shfl_xor(p01, mm);
                        p10 += __shfl_xor(p10, mm);
                        p11 += __shfl_xor(p11, mm);
                    }
                    if (tl == 0) {
                        float* o = out + (size_t)s_id[base + l] * 16;
                        *(float2*)(o + q * 2)     = make_float2(p00, p01);  // q0=0
                        *(float2*)(o + 8 + q * 2) = make_float2(p10, p11);  // q0=1
                    }
                }
            }
        }
    }
#undef LOAD_BATCH
#undef FMA_BATCH
}

extern "C" void kernel_launch(void* const* d_in, const int* in_sizes, int n_in,
                              void* d_out, int out_size, void* d_ws, size_t ws_size,
                              hipStream_t stream) {
    const int*   idx = (const int*)d_in[0];
    const float* c0  = (const float*)d_in[1];
    const float* c1  = (const float*)d_in[2];
    const float* c2  = (const float*)d_in[3];
    float* out = (float*)d_out;
    (void)d_ws; (void)ws_size; (void)in_sizes; (void)n_in; (void)out_size;

    tt_fused<<<dim3(432, 4, 2), dim3(128), 0, stream>>>(idx, c0, c1, c2, out);
}